// Round 7
// baseline (19.053 us; speedup 1.0000x reference)
//
#include <hip/hip_runtime.h>
#include <math.h>

#define L 512
#define TILE_T 16
#define NTHREADS 256
#define NWAVES 4
#define NACT_PAD 104     // active-rows bound ~80 (+4 pad)
#define ZWIN 9.0f        // dropped mass <= exp(-40.5): provably < 1e-10 on output
#define NXCD 8

static constexpr float EPS = 1e-6f;
static constexpr float INV_SQRT_2PI = 0.39894228040143267794f;

__global__ __launch_bounds__(NTHREADS, 8) void ge_kernel(
    const float* __restrict__ text,  // [B, L, D]
    const int*   __restrict__ durs,  // [B, L]
    float*       __restrict__ out,   // [B, T, D]
    int B, int D, int T, int tilesPerB, int nwg)
{
    __shared__ float2 s_mi [NWAVES][NACT_PAD];     // (mean, 1/sigma)
    __shared__ int    s_row[NWAVES][NACT_PAD];
    __shared__ float  s_p  [NWAVES][4][NACT_PAD];  // [wave][tq][item]

    const int tid  = threadIdx.x;
    const int lane = tid & 63;
    const int wid  = tid >> 6;

    // XCD-aware bijective swizzle (nwg % NXCD == 0)
    const int orig = blockIdx.x;
    const int wg   = (orig & (NXCD - 1)) * (nwg / NXCD) + (orig >> 3);
    const int b    = wg / tilesPerB;
    const int t0   = (wg % tilesPerB) * TILE_T;

    // ---- wave-private full cumsum of durs: lane owns rows 8*lane..8*lane+7 ----
    const int r0 = lane << 3;
    const int4* dp = (const int4*)(durs + (size_t)b * L + r0);
    const int4 da = dp[0];
    const int4 db = dp[1];
    int dv[8] = {da.x, da.y, da.z, da.w, db.x, db.y, db.z, db.w};
    int csum[8];
    {
        int run = 0;
        #pragma unroll
        for (int j = 0; j < 8; ++j) { run += dv[j]; csum[j] = run; }
        int v = run;
        #pragma unroll
        for (int off = 1; off < 64; off <<= 1) {
            int n = __shfl_up(v, off, 64);
            if (lane >= off) v += n;
        }
        const int excl = v - run;
        #pragma unroll
        for (int j = 0; j < 8; ++j) csum[j] += excl;   // inclusive cumsum
    }

    const float tlo = (float)t0 + 0.5f;
    const float thi = (float)t0 + (float)TILE_T - 0.5f;

    // ---- act test + in-wave ballot compaction into wave-private list ----
    float meanv[8], isigv[8];
    bool  act[8];
    #pragma unroll
    for (int j = 0; j < 8; ++j) {
        const float d  = (float)dv[j];
        const float m  = (float)csum[j] + 0.5f * d;    // cumsum_incl + d/2
        const float sg = 0.5f * d + EPS;
        meanv[j] = m;
        isigv[j] = 1.0f / sg;
        const float r = ZWIN * sg;
        act[j] = (dv[j] >= 1) && (m + r >= tlo) && (m - r <= thi);
    }
    const unsigned long long ltm = (lane == 0) ? 0ull : ((~0ull) >> (64 - lane));
    int nact = 0;
    #pragma unroll
    for (int j = 0; j < 8; ++j) {
        const unsigned long long mj = __ballot(act[j]);
        if (act[j]) {
            const int idx = nact + (int)__popcll(mj & ltm);
            s_mi [wid][idx] = make_float2(meanv[j], isigv[j]);
            s_row[wid][idx] = r0 + j;
        }
        nact += (int)__popcll(mj);
    }
    // pad 4 entries: zero prob, safe row index
    if (lane < 4) {
        s_row[wid][nact + lane]  = 0;
        s_p[wid][0][nact + lane] = 0.f;
        s_p[wid][1][nact + lane] = 0.f;
        s_p[wid][2][nact + lane] = 0.f;
        s_p[wid][3][nact + lane] = 0.f;
    }
    asm volatile("s_waitcnt lgkmcnt(0)" ::: "memory");   // wave-local LDS RAW fence
    __builtin_amdgcn_sched_barrier(0);

    // ---- stage 1: probs for this wave's 4 t's; accumulate denominators ----
    const float tq = (float)(t0 + (wid << 2)) + 0.5f;
    float ps0 = 0.f, ps1 = 0.f, ps2 = 0.f, ps3 = 0.f;
    for (int base_i = 0; base_i < nact; base_i += 64) {
        const int item = base_i + lane;
        if (item < nact) {
            const float2 mi = s_mi[wid][item];
            const float c  = mi.y * INV_SQRT_2PI;
            const float z0 = (tq + 0.f - mi.x) * mi.y;
            const float z1 = (tq + 1.f - mi.x) * mi.y;
            const float z2 = (tq + 2.f - mi.x) * mi.y;
            const float z3 = (tq + 3.f - mi.x) * mi.y;
            const float p0 = __expf(-0.5f * z0 * z0) * c;
            const float p1 = __expf(-0.5f * z1 * z1) * c;
            const float p2 = __expf(-0.5f * z2 * z2) * c;
            const float p3 = __expf(-0.5f * z3 * z3) * c;
            s_p[wid][0][item] = p0;
            s_p[wid][1][item] = p1;
            s_p[wid][2][item] = p2;
            s_p[wid][3][item] = p3;
            ps0 += p0; ps1 += p1; ps2 += p2; ps3 += p3;
        }
    }
    #pragma unroll
    for (int off = 32; off > 0; off >>= 1) {
        ps0 += __shfl_xor(ps0, off, 64);
        ps1 += __shfl_xor(ps1, off, 64);
        ps2 += __shfl_xor(ps2, off, 64);
        ps3 += __shfl_xor(ps3, off, 64);
    }
    const float rn0 = 1.0f / (ps0 + EPS);
    const float rn1 = 1.0f / (ps1 + EPS);
    const float rn2 = 1.0f / (ps2 + EPS);
    const float rn3 = 1.0f / (ps3 + EPS);
    asm volatile("s_waitcnt lgkmcnt(0)" ::: "memory");   // s_p writes -> broadcast reads
    __builtin_amdgcn_sched_barrier(0);

    // ---- stage 2: 2-row unrolled, 2-deep text prefetch, branch-free via pads ----
    float4 a0 = {0,0,0,0}, a1 = {0,0,0,0}, a2 = {0,0,0,0}, a3 = {0,0,0,0};
    const float* tb = text + (size_t)b * L * D + (lane << 2);
    if (nact > 0) {
        float4 v0 = *(const float4*)(tb + (size_t)s_row[wid][0] * D);
        float4 v1 = *(const float4*)(tb + (size_t)s_row[wid][1] * D);
        const int niter = (nact + 1) & ~1;   // even
        for (int i = 0; i < niter; i += 2) {
            const float4 w0 = v0;
            const float4 w1 = v1;
            v0 = *(const float4*)(tb + (size_t)s_row[wid][i + 2] * D);
            v1 = *(const float4*)(tb + (size_t)s_row[wid][i + 3] * D);
            const float q00 = s_p[wid][0][i],     q10 = s_p[wid][1][i],     q20 = s_p[wid][2][i],     q30 = s_p[wid][3][i];
            const float q01 = s_p[wid][0][i + 1], q11 = s_p[wid][1][i + 1], q21 = s_p[wid][2][i + 1], q31 = s_p[wid][3][i + 1];
            a0.x += q00*w0.x; a0.y += q00*w0.y; a0.z += q00*w0.z; a0.w += q00*w0.w;
            a1.x += q10*w0.x; a1.y += q10*w0.y; a1.z += q10*w0.z; a1.w += q10*w0.w;
            a2.x += q20*w0.x; a2.y += q20*w0.y; a2.z += q20*w0.z; a2.w += q20*w0.w;
            a3.x += q30*w0.x; a3.y += q30*w0.y; a3.z += q30*w0.z; a3.w += q30*w0.w;
            a0.x += q01*w1.x; a0.y += q01*w1.y; a0.z += q01*w1.z; a0.w += q01*w1.w;
            a1.x += q11*w1.x; a1.y += q11*w1.y; a1.z += q11*w1.z; a1.w += q11*w1.w;
            a2.x += q21*w1.x; a2.y += q21*w1.y; a2.z += q21*w1.z; a2.w += q21*w1.w;
            a3.x += q31*w1.x; a3.y += q31*w1.y; a3.z += q31*w1.z; a3.w += q31*w1.w;
        }
    }

    // ---- stage 3: normalize + store (wave owns 4 consecutive t rows) ----
    const int ttq = t0 + (wid << 2);
    float* ob = out + ((size_t)b * T + ttq) * D + (lane << 2);
    if (ttq + 0 < T) *(float4*)(ob + 0*(size_t)D) = make_float4(a0.x*rn0, a0.y*rn0, a0.z*rn0, a0.w*rn0);
    if (ttq + 1 < T) *(float4*)(ob + 1*(size_t)D) = make_float4(a1.x*rn1, a1.y*rn1, a1.z*rn1, a1.w*rn1);
    if (ttq + 2 < T) *(float4*)(ob + 2*(size_t)D) = make_float4(a2.x*rn2, a2.y*rn2, a2.z*rn2, a2.w*rn2);
    if (ttq + 3 < T) *(float4*)(ob + 3*(size_t)D) = make_float4(a3.x*rn3, a3.y*rn3, a3.z*rn3, a3.w*rn3);
}

extern "C" void kernel_launch(void* const* d_in, const int* in_sizes, int n_in,
                              void* d_out, int out_size, void* d_ws, size_t ws_size,
                              hipStream_t stream) {
    const float* text = (const float*)d_in[0];
    const int*   durs = (const int*)d_in[1];
    float*       out  = (float*)d_out;

    const int BL = in_sizes[1];        // B * L
    const int D  = in_sizes[0] / BL;   // 256
    const int B  = BL / L;             // 16
    const int T  = out_size / (B * D); // 2048
    const int tilesPerB = (T + TILE_T - 1) / TILE_T;
    const int nwg = B * tilesPerB;     // 2048, divisible by 8

    ge_kernel<<<dim3(nwg), dim3(NTHREADS), 0, stream>>>(
        text, durs, out, B, D, T, tilesPerB, nwg);
}